// Round 9
// baseline (507.630 us; speedup 1.0000x reference)
//
#include <hip/hip_runtime.h>
#include <hip/hip_bf16.h>
#include <math.h>

#define NMOD 4
#define NB 4
#define NTOKN 1024
#define CDIM 768
#define HDIM 3072
#define RDIM 16
#define MROWS (NMOD*NB*NTOKN)   // 16384 token rows
#define RPM (NB*NTOKN)          // 4096 positions per modality

typedef __bf16 bf16_t;
typedef __bf16 bf16x4 __attribute__((ext_vector_type(4)));
typedef __bf16 bf16x8 __attribute__((ext_vector_type(8)));
typedef float f32x4 __attribute__((ext_vector_type(4)));

// ---------------- f32 -> bf16 convert ----------------
__global__ void cvt_kernel(const float* __restrict__ in, bf16_t* __restrict__ out, int n) {
  int i = (blockIdx.x * blockDim.x + threadIdx.x) * 4;
  if (i >= n) return;
  const float4 v = *reinterpret_cast<const float4*>(in + i);
  bf16x4 o;
  o[0] = (bf16_t)v.x; o[1] = (bf16_t)v.y; o[2] = (bf16_t)v.z; o[3] = (bf16_t)v.w;
  *reinterpret_cast<bf16x4*>(out + i) = o;
}

// ---------------- delta1[k][h][c] = fc1_w[h][c] * (B@A) ----------------
__global__ void delta1_kernel(const float* __restrict__ fc1w, const float* __restrict__ a1,
                              const float* __restrict__ b1, bf16_t* __restrict__ out) {
  int idx = blockIdx.x * blockDim.x + threadIdx.x;
  if (idx >= NMOD*HDIM*CDIM) return;
  int c = idx % CDIM;
  int h = (idx / CDIM) % HDIM;
  int k = idx / (CDIM*HDIM);
  const float* brow = b1 + ((size_t)k*HDIM + h)*RDIM;
  const float* acol = a1 + (size_t)k*RDIM*CDIM + c;
  float s = 0.f;
  #pragma unroll
  for (int r = 0; r < RDIM; ++r) s += brow[r] * acol[r*CDIM];
  out[idx] = (bf16_t)(fc1w[h*CDIM + c] * s);
}

__global__ void delta2_kernel(const float* __restrict__ fc2w, const float* __restrict__ a2,
                              const float* __restrict__ b2, bf16_t* __restrict__ out) {
  int idx = blockIdx.x * blockDim.x + threadIdx.x;
  if (idx >= NMOD*CDIM*HDIM) return;
  int h = idx % HDIM;
  int c = (idx / HDIM) % CDIM;
  int k = idx / (HDIM*CDIM);
  const float* brow = b2 + ((size_t)k*CDIM + c)*RDIM;
  const float* acol = a2 + (size_t)k*RDIM*HDIM + h;
  float s = 0.f;
  #pragma unroll
  for (int r = 0; r < RDIM; ++r) s += brow[r] * acol[r*HDIM];
  out[idx] = (bf16_t)(fc2w[c*HDIM + h] * s);
}

// ---------------- gating: normw[t][k]; fused x->bf16; 4 tokens/block ----------------
__global__ void gate_kernel(const float* __restrict__ x, const float* __restrict__ gw,
                            const float* __restrict__ gb, const int* __restrict__ mask,
                            float* __restrict__ normw, bf16_t* __restrict__ x_bf) {
  int t = blockIdx.x * 4 + (threadIdx.x >> 6);
  int lane = threadIdx.x & 63;
  int i = t >> 12;
  int b = (t >> 10) & 3;
  const float* xr = x + (size_t)t * CDIM;
  bf16_t* xo = x_bf + (size_t)t * CDIM;
  float acc[NMOD] = {0.f, 0.f, 0.f, 0.f};
  for (int c = lane; c < CDIM; c += 64) {
    float xv = xr[c];
    xo[c] = (bf16_t)xv;
    #pragma unroll
    for (int e = 0; e < NMOD; ++e) acc[e] += xv * gw[(i*NMOD + e)*CDIM + c];
  }
  #pragma unroll
  for (int e = 0; e < NMOD; ++e) {
    float v = acc[e];
    #pragma unroll
    for (int off = 32; off > 0; off >>= 1) v += __shfl_xor(v, off);
    acc[e] = v;
  }
  if (lane == 0) {
    float lg[NMOD], mx = -1e30f;
    #pragma unroll
    for (int e = 0; e < NMOD; ++e) { lg[e] = acc[e] + gb[i*NMOD + e]; mx = fmaxf(mx, lg[e]); }
    float s = 0.f;
    #pragma unroll
    for (int e = 0; e < NMOD; ++e) { lg[e] = expf(lg[e] - mx); s += lg[e]; }
    float inv = 1.f / s;
    float num[NMOD], den = 0.f;
    #pragma unroll
    for (int k = 0; k < NMOD; ++k) {
      float mk = (float)mask[k*NB + b];
      num[k] = lg[k] * inv * mk;
      den += num[k];
    }
    float mi = (float)mask[i*NB + b];
    float scale = mi / (den + 1e-6f);
    #pragma unroll
    for (int k = 0; k < NMOD; ++k) normw[(size_t)t*4 + k] = num[k] * scale;
  }
}

// ---------------- bf16 MFMA GEMM: swizzled (r8) + 2-phase stage-ahead (T3 minimum) ----------------
// out[row][col] = A[row,:] . W[col,:]  (W stored [N,K]); chunk of 4P rows.
// grid: (4P/128, N/128, 2); z=0: base W0 (+bias) -> outB; z=1: WL[mod] -> outL (mask-skip).
// Loop: STAGE(buf^1, t+1) -> compute(buf) -> __syncthreads (drains vmcnt0 + publishes) -> swap.
// Staging loads stay in flight UNDER the 32-MFMA compute phase (one barrier/iter, drain after
// compute, not between stage and compute). __syncthreads is a full fence: no r7-style race.
#define BMT 128
#define BNT 128
#define BKT 64

__device__ __forceinline__ void gload_lds16(const bf16_t* g, bf16_t* l) {
  __builtin_amdgcn_global_load_lds((const __attribute__((address_space(1))) void*)g,
                                   (__attribute__((address_space(3))) void*)l, 16, 0, 0);
}
#define MFMA_BF16 __builtin_amdgcn_mfma_f32_16x16x32_bf16

__global__ __launch_bounds__(256, 2)
void gemm_kernel(const bf16_t* __restrict__ A, const bf16_t* __restrict__ W0,
                 const bf16_t* __restrict__ WL, const float* __restrict__ bias,
                 const int* __restrict__ mask,
                 bf16_t* __restrict__ outB, bf16_t* __restrict__ outL,
                 int K, int N, int P, int modStride, int rowOff, int posOff) {
  __shared__ __align__(16) bf16_t lds[2][2][BMT * BKT];   // 64 KiB (double-buffered)

  const int tid  = threadIdx.x;
  const int lane = tid & 63;
  const int wv   = tid >> 6;
  const int wr   = wv >> 1, wc = wv & 1;
  const int row0 = blockIdx.x * BMT;   // chunk-local
  const int col0 = blockIdx.y * BNT;
  const bool lora = (blockIdx.z != 0);

  const int mod = row0 / P;            // P % 128 == 0
  if (lora) {
    const int bb = (posOff + (row0 % P)) >> 10;
    if (mask[mod*NB + bb] == 0) return;    // outputs get weight 0.0 in combine
  }
  const int gArow0 = mod * modStride + rowOff + (row0 % P);
  const bf16_t* Wp = lora ? (WL + (size_t)mod * N * K) : W0;

  // staging: 4 rounds of 32 rows; source col-slot swizzled, LDS dest linear (tid*16B)
  const int ldr = tid >> 3;                    // 0..31 (row; row&7 == ldr&7)
  const int ssl = ((tid & 7) ^ (ldr & 7)) * 8; // swizzled source col (elems)
  const bf16_t* Ag = A  + (size_t)(gArow0 + ldr) * K + ssl;
  const bf16_t* Wg = Wp + (size_t)(col0   + ldr) * K + ssl;

#define STAGE(buf, t) do {                                                      \
    const int ko_ = (t)*BKT;                                                    \
    _Pragma("unroll")                                                           \
    for (int j_ = 0; j_ < 4; ++j_)                                              \
      gload_lds16(Ag + (size_t)(j_*32)*K + ko_, &lds[buf][0][tid*8 + j_*2048]); \
    _Pragma("unroll")                                                           \
    for (int j_ = 0; j_ < 4; ++j_)                                              \
      gload_lds16(Wg + (size_t)(j_*32)*K + ko_, &lds[buf][1][tid*8 + j_*2048]); \
  } while (0)

  // reads: want source slot (kk*4+hi) at row r -> LDS slot (kk*4+hi)^(r&7); r&7 == fr&7
  const int fr  = lane & 15;
  const int hi  = lane >> 4;
  const int sk0 = ((hi)     ^ (fr & 7)) * 8;   // kk=0
  const int sk1 = ((4 + hi) ^ (fr & 7)) * 8;   // kk=1

  f32x4 acc[4][4];
  #pragma unroll
  for (int i = 0; i < 4; ++i)
    #pragma unroll
    for (int j = 0; j < 4; ++j) acc[i][j] = (f32x4){0.f, 0.f, 0.f, 0.f};

  const int NT = K / BKT;

  STAGE(0, 0);
  __syncthreads();                      // drain tile0 (vmcnt(0) before s_barrier)

  int buf = 0;
  for (int t = 0; t < NT; ++t) {
    if (t + 1 < NT) STAGE(buf ^ 1, t + 1);   // issue next-tile loads BEFORE compute
    const bf16_t* As_ = &lds[buf][0][0];
    const bf16_t* Bs_ = &lds[buf][1][0];

    #pragma unroll
    for (int kk = 0; kk < 2; ++kk) {
      const int sk = (kk == 0) ? sk0 : sk1;
      bf16x8 af[4], bfr[4];
      #pragma unroll
      for (int mi = 0; mi < 4; ++mi)
        af[mi] = *reinterpret_cast<const bf16x8*>(&As_[(wr*64 + mi*16 + fr)*BKT + sk]);
      #pragma unroll
      for (int ni = 0; ni < 4; ++ni)
        bfr[ni] = *reinterpret_cast<const bf16x8*>(&Bs_[(wc*64 + ni*16 + fr)*BKT + sk]);
      #pragma unroll
      for (int mi = 0; mi < 4; ++mi)
        #pragma unroll
        for (int ni = 0; ni < 4; ++ni)
          acc[mi][ni] = MFMA_BF16(af[mi], bfr[ni], acc[mi][ni], 0, 0, 0);
    }
    __syncthreads();   // drains stage loads (vmcnt 0) + publishes buf^1 + protects buf
    buf ^= 1;
  }
#undef STAGE

  bf16_t* outp = lora ? outL : outB;
  #pragma unroll
  for (int mi = 0; mi < 4; ++mi) {
    #pragma unroll
    for (int ni = 0; ni < 4; ++ni) {
      const int colg = col0 + wc*64 + ni*16 + fr;
      float bv = 0.f;
      if (!lora) bv = bias[colg];
      #pragma unroll
      for (int rg = 0; rg < 4; ++rg) {
        const int rowg = row0 + wr*64 + mi*16 + hi*4 + rg;  // chunk-local
        outp[(size_t)rowg * N + colg] = (bf16_t)(acc[mi][ni][rg] + bv);
      }
    }
  }
}

// ---------------- combine1: x1 = gelu(base1 + sum_k normw*L1[k]), in-place; mask-skip reads ----------------
__global__ void combine1_kernel(bf16_t* __restrict__ base1, const bf16_t* __restrict__ L1,
                                const float* __restrict__ normw, const int* __restrict__ mask,
                                int P, int chunkOff) {
  int idx = blockIdx.x * blockDim.x + threadIdx.x;
  if (idx >= P * (HDIM/8)) return;
  int h0 = (idx % (HDIM/8)) * 8;
  int p  = idx / (HDIM/8);
  const int b = (chunkOff + p) >> 10;
  float lv[4][8];
  #pragma unroll
  for (int k = 0; k < 4; ++k) {
    if (mask[k*NB + b] != 0) {          // masked streams contribute exactly 0 — skip read
      bf16x8 v = *reinterpret_cast<const bf16x8*>(&L1[((size_t)(k*P + p))*HDIM + h0]);
      #pragma unroll
      for (int j = 0; j < 8; ++j) lv[k][j] = (float)v[j];
    } else {
      #pragma unroll
      for (int j = 0; j < 8; ++j) lv[k][j] = 0.f;
    }
  }
  #pragma unroll
  for (int i = 0; i < 4; ++i) {
    size_t ro = ((size_t)(i*P + p))*HDIM + h0;
    const float* nw = normw + ((size_t)(i*RPM + chunkOff + p))*4;
    float n0 = nw[0], n1 = nw[1], n2 = nw[2], n3 = nw[3];
    bf16x8 bv = *reinterpret_cast<const bf16x8*>(&base1[ro]);
    bf16x8 ov;
    #pragma unroll
    for (int j = 0; j < 8; ++j) {
      float v = (float)bv[j] + n0*lv[0][j] + n1*lv[1][j] + n2*lv[2][j] + n3*lv[3][j];
      float g = 0.5f * v * (1.f + erff(v * 0.70710678118654752f));  // exact gelu
      ov[j] = (bf16_t)g;
    }
    *reinterpret_cast<bf16x8*>(&base1[ro]) = ov;
  }
}

// ---------------- combine2: out = base2 + sum_k normw*L2[k]  (f32 out); mask-skip reads ----------------
__global__ void combine2_kernel(const bf16_t* __restrict__ base2, const bf16_t* __restrict__ L2,
                                const float* __restrict__ normw, const int* __restrict__ mask,
                                float* __restrict__ out, int P, int chunkOff) {
  int idx = blockIdx.x * blockDim.x + threadIdx.x;
  if (idx >= P * (CDIM/8)) return;
  int c0 = (idx % (CDIM/8)) * 8;
  int p  = idx / (CDIM/8);
  const int b = (chunkOff + p) >> 10;
  float lv[4][8];
  #pragma unroll
  for (int k = 0; k < 4; ++k) {
    if (mask[k*NB + b] != 0) {
      bf16x8 v = *reinterpret_cast<const bf16x8*>(&L2[((size_t)(k*P + p))*CDIM + c0]);
      #pragma unroll
      for (int j = 0; j < 8; ++j) lv[k][j] = (float)v[j];
    } else {
      #pragma unroll
      for (int j = 0; j < 8; ++j) lv[k][j] = 0.f;
    }
  }
  #pragma unroll
  for (int i = 0; i < 4; ++i) {
    int grow = i*RPM + chunkOff + p;
    const float* nw = normw + (size_t)grow*4;
    float n0 = nw[0], n1 = nw[1], n2 = nw[2], n3 = nw[3];
    bf16x8 bv = *reinterpret_cast<const bf16x8*>(&base2[((size_t)(i*P + p))*CDIM + c0]);
    float o[8];
    #pragma unroll
    for (int j = 0; j < 8; ++j)
      o[j] = (float)bv[j] + n0*lv[0][j] + n1*lv[1][j] + n2*lv[2][j] + n3*lv[3][j];
    float4* op = reinterpret_cast<float4*>(out + (size_t)grow*CDIM + c0);
    op[0] = make_float4(o[0], o[1], o[2], o[3]);
    op[1] = make_float4(o[4], o[5], o[6], o[7]);
  }
}

extern "C" void kernel_launch(void* const* d_in, const int* in_sizes, int n_in,
                              void* d_out, int out_size, void* d_ws, size_t ws_size,
                              hipStream_t stream) {
  (void)in_sizes; (void)n_in; (void)out_size;
  const float* x    = (const float*)d_in[0];
  const float* fc1w = (const float*)d_in[1];
  const float* fc1b = (const float*)d_in[2];
  const float* fc2w = (const float*)d_in[3];
  const float* fc2b = (const float*)d_in[4];
  const float* a1   = (const float*)d_in[5];
  const float* b1   = (const float*)d_in[6];
  const float* a2   = (const float*)d_in[7];
  const float* b2   = (const float*)d_in[8];
  const float* gw   = (const float*)d_in[9];
  const float* gb   = (const float*)d_in[10];
  const int*   mask = (const int*)d_in[11];
  float* out = (float*)d_out;

  char* ws = (char*)d_ws;
  size_t off = 0;
  auto carve = [&](size_t bytes) -> char* {
    char* p = ws + off; off += (bytes + 255) & ~(size_t)255; return p;
  };
  // fixed buffers: 72.7 MB
  bf16_t* x_bf  = (bf16_t*)carve((size_t)MROWS*CDIM*2);
  bf16_t* w1_bf = (bf16_t*)carve((size_t)HDIM*CDIM*2);
  bf16_t* w2_bf = (bf16_t*)carve((size_t)CDIM*HDIM*2);
  bf16_t* d1_bf = (bf16_t*)carve((size_t)NMOD*HDIM*CDIM*2);
  bf16_t* d2_bf = (bf16_t*)carve((size_t)NMOD*CDIM*HDIM*2);
  float*  normw = (float*)carve((size_t)MROWS*4*4);
  const size_t fixedBytes = off;

  // chunk size P (positions; 4P rows/GEMM): 61440*P bytes/chunk
  int P = RPM;  // 4096
  while (P > 128 && fixedBytes + (size_t)61440*P + 4096 > ws_size) P >>= 1;
  const int NCH = RPM / P;

  bf16_t* base1 = (bf16_t*)carve((size_t)NMOD*P*HDIM*2);  // becomes x1 in-place
  bf16_t* L1    = (bf16_t*)carve((size_t)NMOD*P*HDIM*2);
  bf16_t* base2 = (bf16_t*)carve((size_t)NMOD*P*CDIM*2);
  bf16_t* L2    = (bf16_t*)carve((size_t)NMOD*P*CDIM*2);

  // precompute (independent)
  cvt_kernel<<<HDIM*CDIM/1024, 256, 0, stream>>>(fc1w, w1_bf, HDIM*CDIM);
  cvt_kernel<<<CDIM*HDIM/1024, 256, 0, stream>>>(fc2w, w2_bf, CDIM*HDIM);
  delta1_kernel<<<NMOD*HDIM*CDIM/256, 256, 0, stream>>>(fc1w, a1, b1, d1_bf);
  delta2_kernel<<<NMOD*CDIM*HDIM/256, 256, 0, stream>>>(fc2w, a2, b2, d2_bf);
  gate_kernel<<<MROWS/4, 256, 0, stream>>>(x, gw, gb, mask, normw, x_bf);

  for (int g = 0; g < NCH; ++g) {
    const int chunkOff = g * P;
    // stage 1: base fc1 + lora1 over 4P rows (K=768)
    gemm_kernel<<<dim3(NMOD*P/BMT, HDIM/BNT, 2), 256, 0, stream>>>(
        x_bf, w1_bf, d1_bf, fc1b, mask, base1, L1, CDIM, HDIM, P, RPM, chunkOff, chunkOff);
    combine1_kernel<<<(P*(HDIM/8) + 255)/256, 256, 0, stream>>>(base1, L1, normw, mask, P, chunkOff);
    // stage 2: base fc2 + lora2 (A = x1 in base1; K=3072)
    gemm_kernel<<<dim3(NMOD*P/BMT, CDIM/BNT, 2), 256, 0, stream>>>(
        base1, w2_bf, d2_bf, fc2b, mask, base2, L2, HDIM, CDIM, P, P, 0, chunkOff);
    combine2_kernel<<<(P*(CDIM/8) + 255)/256, 256, 0, stream>>>(base2, L2, normw, mask, out, P, chunkOff);
  }
}

// Round 10
// 454.186 us; speedup vs baseline: 1.1177x; 1.1177x over previous
//
#include <hip/hip_runtime.h>
#include <hip/hip_bf16.h>
#include <math.h>

#define NMOD 4
#define NB 4
#define NTOKN 1024
#define CDIM 768
#define HDIM 3072
#define RDIM 16
#define MROWS (NMOD*NB*NTOKN)   // 16384 token rows
#define RPM (NB*NTOKN)          // 4096 positions per modality

typedef __bf16 bf16_t;
typedef __bf16 bf16x4 __attribute__((ext_vector_type(4)));
typedef __bf16 bf16x8 __attribute__((ext_vector_type(8)));
typedef float f32x4 __attribute__((ext_vector_type(4)));

// ---------------- f32 -> bf16 convert ----------------
__global__ void cvt_kernel(const float* __restrict__ in, bf16_t* __restrict__ out, int n) {
  int i = (blockIdx.x * blockDim.x + threadIdx.x) * 4;
  if (i >= n) return;
  const float4 v = *reinterpret_cast<const float4*>(in + i);
  bf16x4 o;
  o[0] = (bf16_t)v.x; o[1] = (bf16_t)v.y; o[2] = (bf16_t)v.z; o[3] = (bf16_t)v.w;
  *reinterpret_cast<bf16x4*>(out + i) = o;
}

// ---------------- delta1[k][h][c] = fc1_w[h][c] * (B@A) ----------------
__global__ void delta1_kernel(const float* __restrict__ fc1w, const float* __restrict__ a1,
                              const float* __restrict__ b1, bf16_t* __restrict__ out) {
  int idx = blockIdx.x * blockDim.x + threadIdx.x;
  if (idx >= NMOD*HDIM*CDIM) return;
  int c = idx % CDIM;
  int h = (idx / CDIM) % HDIM;
  int k = idx / (CDIM*HDIM);
  const float* brow = b1 + ((size_t)k*HDIM + h)*RDIM;
  const float* acol = a1 + (size_t)k*RDIM*CDIM + c;
  float s = 0.f;
  #pragma unroll
  for (int r = 0; r < RDIM; ++r) s += brow[r] * acol[r*CDIM];
  out[idx] = (bf16_t)(fc1w[h*CDIM + c] * s);
}

__global__ void delta2_kernel(const float* __restrict__ fc2w, const float* __restrict__ a2,
                              const float* __restrict__ b2, bf16_t* __restrict__ out) {
  int idx = blockIdx.x * blockDim.x + threadIdx.x;
  if (idx >= NMOD*CDIM*HDIM) return;
  int h = idx % HDIM;
  int c = (idx / HDIM) % CDIM;
  int k = idx / (HDIM*CDIM);
  const float* brow = b2 + ((size_t)k*CDIM + c)*RDIM;
  const float* acol = a2 + (size_t)k*RDIM*HDIM + h;
  float s = 0.f;
  #pragma unroll
  for (int r = 0; r < RDIM; ++r) s += brow[r] * acol[r*HDIM];
  out[idx] = (bf16_t)(fc2w[c*HDIM + h] * s);
}

// ---------------- gating: normw[t][k]; fused x->bf16; 4 tokens/block ----------------
__global__ void gate_kernel(const float* __restrict__ x, const float* __restrict__ gw,
                            const float* __restrict__ gb, const int* __restrict__ mask,
                            float* __restrict__ normw, bf16_t* __restrict__ x_bf) {
  int t = blockIdx.x * 4 + (threadIdx.x >> 6);
  int lane = threadIdx.x & 63;
  int i = t >> 12;
  int b = (t >> 10) & 3;
  const float* xr = x + (size_t)t * CDIM;
  bf16_t* xo = x_bf + (size_t)t * CDIM;
  float acc[NMOD] = {0.f, 0.f, 0.f, 0.f};
  for (int c = lane; c < CDIM; c += 64) {
    float xv = xr[c];
    xo[c] = (bf16_t)xv;
    #pragma unroll
    for (int e = 0; e < NMOD; ++e) acc[e] += xv * gw[(i*NMOD + e)*CDIM + c];
  }
  #pragma unroll
  for (int e = 0; e < NMOD; ++e) {
    float v = acc[e];
    #pragma unroll
    for (int off = 32; off > 0; off >>= 1) v += __shfl_xor(v, off);
    acc[e] = v;
  }
  if (lane == 0) {
    float lg[NMOD], mx = -1e30f;
    #pragma unroll
    for (int e = 0; e < NMOD; ++e) { lg[e] = acc[e] + gb[i*NMOD + e]; mx = fmaxf(mx, lg[e]); }
    float s = 0.f;
    #pragma unroll
    for (int e = 0; e < NMOD; ++e) { lg[e] = expf(lg[e] - mx); s += lg[e]; }
    float inv = 1.f / s;
    float num[NMOD], den = 0.f;
    #pragma unroll
    for (int k = 0; k < NMOD; ++k) {
      float mk = (float)mask[k*NB + b];
      num[k] = lg[k] * inv * mk;
      den += num[k];
    }
    float mi = (float)mask[i*NB + b];
    float scale = mi / (den + 1e-6f);
    #pragma unroll
    for (int k = 0; k < NMOD; ++k) normw[(size_t)t*4 + k] = num[k] * scale;
  }
}

// ---------------- bf16 MFMA GEMM (r8 structure, swizzled, 4 blocks/CU) ----------------
// out[row][col] = A[row,:] . W[col,:]  (W stored [N,K]); chunk of 4P rows.
// grid: (4P/128, N/128, 2); z=0: base W0 (+bias) -> outB; z=1: WL[mod] -> outL (mask-skip).
// r8-exact loop (stage -> sync -> compute -> sync); ONE change: launch_bounds 2 -> 4
// blocks/CU (VGPR 64, LDS 32KiB x4 = 128 <= 160) for cross-block latency hiding.
#define BMT 128
#define BNT 128
#define BKT 64

__device__ __forceinline__ void gload_lds16(const bf16_t* g, bf16_t* l) {
  __builtin_amdgcn_global_load_lds((const __attribute__((address_space(1))) void*)g,
                                   (__attribute__((address_space(3))) void*)l, 16, 0, 0);
}
#define MFMA_BF16 __builtin_amdgcn_mfma_f32_16x16x32_bf16

__global__ __launch_bounds__(256, 4)
void gemm_kernel(const bf16_t* __restrict__ A, const bf16_t* __restrict__ W0,
                 const bf16_t* __restrict__ WL, const float* __restrict__ bias,
                 const int* __restrict__ mask,
                 bf16_t* __restrict__ outB, bf16_t* __restrict__ outL,
                 int K, int N, int P, int modStride, int rowOff, int posOff) {
  __shared__ __align__(16) bf16_t As[BMT * BKT];
  __shared__ __align__(16) bf16_t Bs[BNT * BKT];

  const int tid  = threadIdx.x;
  const int lane = tid & 63;
  const int wv   = tid >> 6;
  const int wr   = wv >> 1, wc = wv & 1;
  const int row0 = blockIdx.x * BMT;   // chunk-local
  const int col0 = blockIdx.y * BNT;
  const bool lora = (blockIdx.z != 0);

  const int mod = row0 / P;            // P % 128 == 0
  if (lora) {
    const int bb = (posOff + (row0 % P)) >> 10;
    if (mask[mod*NB + bb] == 0) return;    // outputs get weight 0.0 in combine
  }
  const int gArow0 = mod * modStride + rowOff + (row0 % P);
  const bf16_t* Wp = lora ? (WL + (size_t)mod * N * K) : W0;

  // staging: 4 rounds of 32 rows; source col-slot swizzled, LDS dest linear (tid*16B)
  const int ldr = tid >> 3;                    // 0..31 (row; row&7 == ldr&7)
  const int ssl = ((tid & 7) ^ (ldr & 7)) * 8; // swizzled source col (elems)
  const bf16_t* Ag = A  + (size_t)(gArow0 + ldr) * K + ssl;
  const bf16_t* Wg = Wp + (size_t)(col0   + ldr) * K + ssl;

  // reads: want source slot (kk*4+hi) at row r -> LDS slot (kk*4+hi)^(r&7); r&7 == fr&7
  const int fr  = lane & 15;
  const int hi  = lane >> 4;
  const int sk0 = ((hi)     ^ (fr & 7)) * 8;   // kk=0
  const int sk1 = ((4 + hi) ^ (fr & 7)) * 8;   // kk=1

  f32x4 acc[4][4];
  #pragma unroll
  for (int i = 0; i < 4; ++i)
    #pragma unroll
    for (int j = 0; j < 4; ++j) acc[i][j] = (f32x4){0.f, 0.f, 0.f, 0.f};

  for (int k0 = 0; k0 < K; k0 += BKT) {
    __syncthreads();  // protect LDS from overwrite while others still read
    #pragma unroll
    for (int j = 0; j < 4; ++j)
      gload_lds16(Ag + (size_t)(j*32) * K + k0, &As[tid*8 + j*2048]);
    #pragma unroll
    for (int j = 0; j < 4; ++j)
      gload_lds16(Wg + (size_t)(j*32) * K + k0, &Bs[tid*8 + j*2048]);
    __syncthreads();  // drains vmcnt(0) before s_barrier

    #pragma unroll
    for (int kk = 0; kk < 2; ++kk) {
      const int sk = (kk == 0) ? sk0 : sk1;
      bf16x8 af[4], bfr[4];
      #pragma unroll
      for (int mi = 0; mi < 4; ++mi)
        af[mi] = *reinterpret_cast<const bf16x8*>(&As[(wr*64 + mi*16 + fr)*BKT + sk]);
      #pragma unroll
      for (int ni = 0; ni < 4; ++ni)
        bfr[ni] = *reinterpret_cast<const bf16x8*>(&Bs[(wc*64 + ni*16 + fr)*BKT + sk]);
      #pragma unroll
      for (int mi = 0; mi < 4; ++mi)
        #pragma unroll
        for (int ni = 0; ni < 4; ++ni)
          acc[mi][ni] = MFMA_BF16(af[mi], bfr[ni], acc[mi][ni], 0, 0, 0);
    }
  }

  bf16_t* outp = lora ? outL : outB;
  #pragma unroll
  for (int mi = 0; mi < 4; ++mi) {
    #pragma unroll
    for (int ni = 0; ni < 4; ++ni) {
      const int colg = col0 + wc*64 + ni*16 + fr;
      float bv = 0.f;
      if (!lora) bv = bias[colg];
      #pragma unroll
      for (int rg = 0; rg < 4; ++rg) {
        const int rowg = row0 + wr*64 + mi*16 + hi*4 + rg;  // chunk-local
        outp[(size_t)rowg * N + colg] = (bf16_t)(acc[mi][ni][rg] + bv);
      }
    }
  }
}

// ---------------- combine1: x1 = gelu(base1 + sum_k normw*L1[k]), in-place; mask-skip reads ----------------
__global__ void combine1_kernel(bf16_t* __restrict__ base1, const bf16_t* __restrict__ L1,
                                const float* __restrict__ normw, const int* __restrict__ mask,
                                int P, int chunkOff) {
  int idx = blockIdx.x * blockDim.x + threadIdx.x;
  if (idx >= P * (HDIM/8)) return;
  int h0 = (idx % (HDIM/8)) * 8;
  int p  = idx / (HDIM/8);
  const int b = (chunkOff + p) >> 10;
  float lv[4][8];
  #pragma unroll
  for (int k = 0; k < 4; ++k) {
    if (mask[k*NB + b] != 0) {          // masked streams contribute exactly 0 — skip read
      bf16x8 v = *reinterpret_cast<const bf16x8*>(&L1[((size_t)(k*P + p))*HDIM + h0]);
      #pragma unroll
      for (int j = 0; j < 8; ++j) lv[k][j] = (float)v[j];
    } else {
      #pragma unroll
      for (int j = 0; j < 8; ++j) lv[k][j] = 0.f;
    }
  }
  #pragma unroll
  for (int i = 0; i < 4; ++i) {
    size_t ro = ((size_t)(i*P + p))*HDIM + h0;
    const float* nw = normw + ((size_t)(i*RPM + chunkOff + p))*4;
    float n0 = nw[0], n1 = nw[1], n2 = nw[2], n3 = nw[3];
    bf16x8 bv = *reinterpret_cast<const bf16x8*>(&base1[ro]);
    bf16x8 ov;
    #pragma unroll
    for (int j = 0; j < 8; ++j) {
      float v = (float)bv[j] + n0*lv[0][j] + n1*lv[1][j] + n2*lv[2][j] + n3*lv[3][j];
      float g = 0.5f * v * (1.f + erff(v * 0.70710678118654752f));  // exact gelu
      ov[j] = (bf16_t)g;
    }
    *reinterpret_cast<bf16x8*>(&base1[ro]) = ov;
  }
}

// ---------------- combine2: out = base2 + sum_k normw*L2[k]  (f32 out); mask-skip reads ----------------
__global__ void combine2_kernel(const bf16_t* __restrict__ base2, const bf16_t* __restrict__ L2,
                                const float* __restrict__ normw, const int* __restrict__ mask,
                                float* __restrict__ out, int P, int chunkOff) {
  int idx = blockIdx.x * blockDim.x + threadIdx.x;
  if (idx >= P * (CDIM/8)) return;
  int c0 = (idx % (CDIM/8)) * 8;
  int p  = idx / (CDIM/8);
  const int b = (chunkOff + p) >> 10;
  float lv[4][8];
  #pragma unroll
  for (int k = 0; k < 4; ++k) {
    if (mask[k*NB + b] != 0) {
      bf16x8 v = *reinterpret_cast<const bf16x8*>(&L2[((size_t)(k*P + p))*CDIM + c0]);
      #pragma unroll
      for (int j = 0; j < 8; ++j) lv[k][j] = (float)v[j];
    } else {
      #pragma unroll
      for (int j = 0; j < 8; ++j) lv[k][j] = 0.f;
    }
  }
  #pragma unroll
  for (int i = 0; i < 4; ++i) {
    int grow = i*RPM + chunkOff + p;
    const float* nw = normw + (size_t)grow*4;
    float n0 = nw[0], n1 = nw[1], n2 = nw[2], n3 = nw[3];
    bf16x8 bv = *reinterpret_cast<const bf16x8*>(&base2[((size_t)(i*P + p))*CDIM + c0]);
    float o[8];
    #pragma unroll
    for (int j = 0; j < 8; ++j)
      o[j] = (float)bv[j] + n0*lv[0][j] + n1*lv[1][j] + n2*lv[2][j] + n3*lv[3][j];
    float4* op = reinterpret_cast<float4*>(out + (size_t)grow*CDIM + c0);
    op[0] = make_float4(o[0], o[1], o[2], o[3]);
    op[1] = make_float4(o[4], o[5], o[6], o[7]);
  }
}

extern "C" void kernel_launch(void* const* d_in, const int* in_sizes, int n_in,
                              void* d_out, int out_size, void* d_ws, size_t ws_size,
                              hipStream_t stream) {
  (void)in_sizes; (void)n_in; (void)out_size;
  const float* x    = (const float*)d_in[0];
  const float* fc1w = (const float*)d_in[1];
  const float* fc1b = (const float*)d_in[2];
  const float* fc2w = (const float*)d_in[3];
  const float* fc2b = (const float*)d_in[4];
  const float* a1   = (const float*)d_in[5];
  const float* b1   = (const float*)d_in[6];
  const float* a2   = (const float*)d_in[7];
  const float* b2   = (const float*)d_in[8];
  const float* gw   = (const float*)d_in[9];
  const float* gb   = (const float*)d_in[10];
  const int*   mask = (const int*)d_in[11];
  float* out = (float*)d_out;

  char* ws = (char*)d_ws;
  size_t off = 0;
  auto carve = [&](size_t bytes) -> char* {
    char* p = ws + off; off += (bytes + 255) & ~(size_t)255; return p;
  };
  // fixed buffers: 72.7 MB
  bf16_t* x_bf  = (bf16_t*)carve((size_t)MROWS*CDIM*2);
  bf16_t* w1_bf = (bf16_t*)carve((size_t)HDIM*CDIM*2);
  bf16_t* w2_bf = (bf16_t*)carve((size_t)CDIM*HDIM*2);
  bf16_t* d1_bf = (bf16_t*)carve((size_t)NMOD*HDIM*CDIM*2);
  bf16_t* d2_bf = (bf16_t*)carve((size_t)NMOD*CDIM*HDIM*2);
  float*  normw = (float*)carve((size_t)MROWS*4*4);
  const size_t fixedBytes = off;

  // chunk size P (positions; 4P rows/GEMM): 61440*P bytes/chunk
  int P = RPM;  // 4096
  while (P > 128 && fixedBytes + (size_t)61440*P + 4096 > ws_size) P >>= 1;
  const int NCH = RPM / P;

  bf16_t* base1 = (bf16_t*)carve((size_t)NMOD*P*HDIM*2);  // becomes x1 in-place
  bf16_t* L1    = (bf16_t*)carve((size_t)NMOD*P*HDIM*2);
  bf16_t* base2 = (bf16_t*)carve((size_t)NMOD*P*CDIM*2);
  bf16_t* L2    = (bf16_t*)carve((size_t)NMOD*P*CDIM*2);

  // precompute (independent)
  cvt_kernel<<<HDIM*CDIM/1024, 256, 0, stream>>>(fc1w, w1_bf, HDIM*CDIM);
  cvt_kernel<<<CDIM*HDIM/1024, 256, 0, stream>>>(fc2w, w2_bf, CDIM*HDIM);
  delta1_kernel<<<NMOD*HDIM*CDIM/256, 256, 0, stream>>>(fc1w, a1, b1, d1_bf);
  delta2_kernel<<<NMOD*CDIM*HDIM/256, 256, 0, stream>>>(fc2w, a2, b2, d2_bf);
  gate_kernel<<<MROWS/4, 256, 0, stream>>>(x, gw, gb, mask, normw, x_bf);

  for (int g = 0; g < NCH; ++g) {
    const int chunkOff = g * P;
    // stage 1: base fc1 + lora1 over 4P rows (K=768)
    gemm_kernel<<<dim3(NMOD*P/BMT, HDIM/BNT, 2), 256, 0, stream>>>(
        x_bf, w1_bf, d1_bf, fc1b, mask, base1, L1, CDIM, HDIM, P, RPM, chunkOff, chunkOff);
    combine1_kernel<<<(P*(HDIM/8) + 255)/256, 256, 0, stream>>>(base1, L1, normw, mask, P, chunkOff);
    // stage 2: base fc2 + lora2 (A = x1 in base1; K=3072)
    gemm_kernel<<<dim3(NMOD*P/BMT, CDIM/BNT, 2), 256, 0, stream>>>(
        base1, w2_bf, d2_bf, fc2b, mask, base2, L2, HDIM, CDIM, P, P, 0, chunkOff);
    combine2_kernel<<<(P*(CDIM/8) + 255)/256, 256, 0, stream>>>(base2, L2, normw, mask, out, P, chunkOff);
  }
}